// Round 4
// baseline (335.916 us; speedup 1.0000x reference)
//
#include <hip/hip_runtime.h>
#include <math.h>

typedef __bf16 bf16x8 __attribute__((ext_vector_type(8)));
typedef float f32x4 __attribute__((ext_vector_type(4)));
typedef unsigned short u16;
typedef u16 u16x8 __attribute__((ext_vector_type(8)));

// clip(round(x*inv), -128, 127) -- rintf = round-half-even, matches jnp.round
__device__ __forceinline__ float quantq_inv(float x, float inv) {
    return fminf(fmaxf(rintf(x * inv), -128.f), 127.f);
}

__device__ __forceinline__ u16 sign_bf16(float w) {
    return (w > 0.f) ? (u16)0x3F80 : ((w < 0.f) ? (u16)0xBF80 : (u16)0);
}

// ---------------- prep 1: per-slice |w| partial sums (deterministic) --------
__global__ void alpha_part(const float* __restrict__ w1,
                           const float* __restrict__ w2,
                           const float* __restrict__ w3,
                           float* __restrict__ partial) {
    __shared__ float red[256];
    const int bid = blockIdx.x;
    const int m = bid >> 5, i = bid & 31;
    const float* w = (m == 0) ? w1 : ((m == 1) ? w2 : w3);
    const int n = (m == 0) ? 100352 : ((m == 1) ? 16384 : 1280);
    const int chunk = n >> 5;  // all divisible by 32
    const float* p = w + i * chunk;
    float s = 0.f;
    for (int t = threadIdx.x; t < chunk; t += 256) s += fabsf(p[t]);
    red[threadIdx.x] = s;
    __syncthreads();
    for (int off = 128; off > 0; off >>= 1) {
        if ((int)threadIdx.x < off) red[threadIdx.x] += red[threadIdx.x + off];
        __syncthreads();
    }
    if (threadIdx.x == 0) partial[bid] = red[0];
}

// ---------------- prep 2: pack sign(w) frag-ready + finalize alphas ---------
// dest layout per kstep(K=32): [ntile][lane][8] where for B-operand of
// mfma_f32_16x16x32_bf16: lane = (kk/8)*16 + (col%16), j = kk%8
__global__ void pack_kernel(const float* __restrict__ w1,
                            const float* __restrict__ w2,
                            const float* __restrict__ w3,
                            u16* __restrict__ Wb1,
                            const float* __restrict__ partial,
                            float* __restrict__ alphas) {
    if (blockIdx.x == 0 && threadIdx.x < 3) {
        const int t = threadIdx.x;
        float s = 0.f;
        for (int i = 0; i < 32; ++i) s += partial[t * 32 + i];
        const int n = (t == 0) ? 100352 : ((t == 1) ? 16384 : 1280);
        alphas[t] = s / (float)n;
    }
    u16* Wb2 = Wb1 + 102400;
    u16* Wb3 = Wb2 + 16384;
    int idx = blockIdx.x * 256 + threadIdx.x;
    if (idx < 102400) {
        int k = idx >> 7, n = idx & 127;
        u16 v = (k < 784) ? sign_bf16(w1[k * 128 + n]) : (u16)0;
        int dest = ((((k >> 5) * 8 + (n >> 4)) * 64) + ((((k & 31) >> 3) << 4) | (n & 15))) * 8 + (k & 7);
        Wb1[dest] = v;
    } else if (idx < 102400 + 16384) {
        int i = idx - 102400;
        int k = i >> 7, n = i & 127;
        u16 v = sign_bf16(w2[k * 128 + n]);
        int dest = ((((k >> 5) * 8 + (n >> 4)) * 64) + ((((k & 31) >> 3) << 4) | (n & 15))) * 8 + (k & 7);
        Wb2[dest] = v;
    } else if (idx < 102400 + 16384 + 2048) {
        int i = idx - 102400 - 16384;
        int k = i >> 4, n = i & 15;
        u16 v = (n < 10) ? sign_bf16(w3[k * 10 + n]) : (u16)0;
        int dest = (((k >> 5) * 64) + ((((k & 31) >> 3) << 4) | n)) * 8 + (k & 7);
        Wb3[dest] = v;
    }
}

// ---------------- fused forward: 64 rows/block, 8 waves, split-K layer 1 ----
// waves 0-3 (khalf=0): ksteps 0..11 ; waves 4-7 (khalf=1): ksteps 12..24.
// Partials exchanged via LDS (exact integer fp32 sums), khalf=1 waves exit.
__global__ __launch_bounds__(512, 8) void fused_kernel(
    const float* __restrict__ input,
    const float* __restrict__ bias1, const float* __restrict__ bias2,
    const float* __restrict__ bias3,
    const float* __restrict__ ps_in, const float* __restrict__ ps1i,
    const float* __restrict__ ps1o, const float* __restrict__ ps2i,
    const float* __restrict__ ps2o, const float* __restrict__ ps3i,
    const float* __restrict__ ps3o,
    const float* __restrict__ alphas, const u16* __restrict__ Wb1,
    float* __restrict__ out0, float* __restrict__ h0, float* __restrict__ h1,
    float* __restrict__ h2, float* __restrict__ h3)
{
    const u16* Wb2 = Wb1 + 102400;
    const u16* Wb3 = Wb2 + 16384;

    __shared__ f32x4 Xch[1024];  // 16KB: [wq(4)][nsub(4)][lane(64)]
    __shared__ u16 A2[8192];     // 16KB: [ks(4)][wq(4)][lane(64)][8]

    const int tid = threadIdx.x;
    const int wave = tid >> 6, lane = tid & 63;
    const int wq = wave & 3, khalf = wave >> 2;
    const int row0 = blockIdx.x * 64;

    const float s_in = *ps_in, s1i = *ps1i, s1o = *ps1o;
    const float s2i = *ps2i, s2o = *ps2o, s3i = *ps3i, s3o = *ps3o;
    const float inv_sin = 1.f / s_in, inv_s1i = 1.f / s1i, inv_s1o = 1.f / s1o;
    const float inv_s2i = 1.f / s2i, inv_s2o = 1.f / s2o;
    const float inv_s3i = 1.f / s3i, inv_s3o = 1.f / s3o;
    const float alpha1 = alphas[0], alpha2 = alphas[1], alpha3 = alphas[2];

    // A-frag ownership: row = lane&15 (within wq's 16-row tile), kgroup = lane>>4
    const int rA = lane & 15;
    const int gA = lane >> 4;
    const size_t arow = (size_t)(row0 + wq * 16 + rA) * 784;
    const float* __restrict__ inA = input + arow + gA * 8;
    float* __restrict__ h0A = h0 + arow + gA * 8;
    const u16* bw1 = Wb1 + (size_t)lane * 8;

    f32x4 acc1[8];
#pragma unroll
    for (int n = 0; n < 8; ++n) acc1[n] = f32x4{0.f, 0.f, 0.f, 0.f};

    // quant + h0-store + pack + 8 MFMAs for one kstep's 8 owned elements
    auto consume = [&](int ksq, f32x4 va, f32x4 vb, bool dostore) {
        float q[8];
#pragma unroll
        for (int j = 0; j < 4; ++j) {
            q[j]     = quantq_inv(va[j], inv_sin);
            q[4 + j] = quantq_inv(vb[j], inv_sin);
        }
        if (dostore) {
            f32x4 ha = {q[0] * s_in, q[1] * s_in, q[2] * s_in, q[3] * s_in};
            f32x4 hb = {q[4] * s_in, q[5] * s_in, q[6] * s_in, q[7] * s_in};
            float* hp = h0A + ksq * 32;
            __builtin_nontemporal_store(ha, reinterpret_cast<f32x4*>(hp));
            __builtin_nontemporal_store(hb, reinterpret_cast<f32x4*>(hp + 4));
        }
        u16x8 qb;
#pragma unroll
        for (int j = 0; j < 8; ++j) qb[j] = (u16)(__float_as_uint(q[j]) >> 16);
        union { u16x8 u; bf16x8 b; } cvt;
        cvt.u = qb;
        const bf16x8 a = cvt.b;
        const u16* bp = bw1 + (size_t)ksq * 4096;
#pragma unroll
        for (int n = 0; n < 8; ++n) {
            const bf16x8 b = *reinterpret_cast<const bf16x8*>(bp + n * 512);
            acc1[n] = __builtin_amdgcn_mfma_f32_16x16x32_bf16(a, b, acc1[n], 0, 0, 0);
        }
    };

    // ---- layer 1, split-K, 2-deep static ring ----
    if (khalf == 0) {
        f32x4 pa = *reinterpret_cast<const f32x4*>(inA + 0);
        f32x4 pb = *reinterpret_cast<const f32x4*>(inA + 4);
        f32x4 qa = *reinterpret_cast<const f32x4*>(inA + 32);
        f32x4 qb = *reinterpret_cast<const f32x4*>(inA + 36);
#pragma unroll
        for (int k = 0; k < 12; ++k) {
            f32x4 na = pa, nb = pb;
            if (k + 2 < 12) {
                na = *reinterpret_cast<const f32x4*>(inA + (k + 2) * 32);
                nb = *reinterpret_cast<const f32x4*>(inA + (k + 2) * 32 + 4);
            }
            consume(k, pa, pb, true);
            pa = qa; pb = qb; qa = na; qb = nb;
        }
    } else {
        f32x4 pa = *reinterpret_cast<const f32x4*>(inA + 12 * 32);
        f32x4 pb = *reinterpret_cast<const f32x4*>(inA + 12 * 32 + 4);
        f32x4 qa = *reinterpret_cast<const f32x4*>(inA + 13 * 32);
        f32x4 qb = *reinterpret_cast<const f32x4*>(inA + 13 * 32 + 4);
#pragma unroll
        for (int k = 0; k < 13; ++k) {
            const int ksq = 12 + k;
            const int t = ksq + 2;
            f32x4 na, nb;
            if (t < 24) {
                na = *reinterpret_cast<const f32x4*>(inA + t * 32);
                nb = *reinterpret_cast<const f32x4*>(inA + t * 32 + 4);
            } else if (t == 24) {
                if (gA < 2) {
                    na = *reinterpret_cast<const f32x4*>(inA + 768);
                    nb = *reinterpret_cast<const f32x4*>(inA + 768 + 4);
                } else {
                    na = f32x4{0.f, 0.f, 0.f, 0.f};
                    nb = f32x4{0.f, 0.f, 0.f, 0.f};
                }
            } else {
                na = pa; nb = pb;
            }
            // tail kstep 24: store only valid cols (gA<2); gA>=2 slots hold
            // exact zeros -> q=0 -> zero A-frag (B also zero-padded there)
            consume(ksq, pa, pb, (ksq < 24) || (gA < 2));
            pa = qa; pb = qb; qa = na; qb = nb;
        }
    }

    // ---- split-K exchange: 2 rounds of 16KB, exact integer fp32 adds ----
    if (khalf == 1) {
#pragma unroll
        for (int n = 0; n < 4; ++n) Xch[(wq * 4 + n) * 64 + lane] = acc1[n];
    }
    __syncthreads();
    if (khalf == 0) {
#pragma unroll
        for (int n = 0; n < 4; ++n) acc1[n] += Xch[(wq * 4 + n) * 64 + lane];
    }
    __syncthreads();
    if (khalf == 1) {
#pragma unroll
        for (int n = 0; n < 4; ++n) Xch[(wq * 4 + n) * 64 + lane] = acc1[4 + n];
    }
    __syncthreads();
    if (khalf == 1) return;  // done: remaining phases are tiny, khalf0-only
#pragma unroll
    for (int n = 0; n < 4; ++n) acc1[4 + n] += Xch[(wq * 4 + n) * 64 + lane];

    // ---- layer 1 epilogue: requantize, write h1, restage A2 (wave-local) ----
    const int cl = lane & 15;
    const int rh = lane >> 4;
    {
        const float a1s = alpha1 * s_in;
#pragma unroll
        for (int n = 0; n < 8; ++n) {
            const int col = n * 16 + cl;
            const float bias = bias1[col];
            const int ks = n >> 1;
            const int gk = ((n & 1) * 2) + (cl >> 3);
            const int jd = cl & 7;
#pragma unroll
            for (int j = 0; j < 4; ++j) {
                const int rl = rh * 4 + j;
                float x = a1s * acc1[n][j] + bias;
                x = quantq_inv(x, inv_s1i) * s1i;
                x = fmaxf(x, 0.f);
                const float qv = quantq_inv(x, inv_s1o);
                __builtin_nontemporal_store(qv * s1o,
                    h1 + (size_t)(row0 + wq * 16 + rl) * 128 + col);
                A2[(((ks * 4 + wq) * 64) + (gk * 16 + rl)) * 8 + jd] =
                    (u16)(__float_as_uint(qv) >> 16);
            }
        }
    }

    // ---- layer 2: K=128 (4 ksteps), B-frags straight from global (L1) ----
    f32x4 acc2[8];
#pragma unroll
    for (int n = 0; n < 8; ++n) acc2[n] = f32x4{0.f, 0.f, 0.f, 0.f};
#pragma unroll
    for (int ks = 0; ks < 4; ++ks) {
        const bf16x8 a = *reinterpret_cast<const bf16x8*>(&A2[((ks * 4 + wq) * 64 + lane) * 8]);
#pragma unroll
        for (int n = 0; n < 8; ++n) {
            const bf16x8 b = *reinterpret_cast<const bf16x8*>(Wb2 + ((size_t)(ks * 8 + n) * 64 + lane) * 8);
            acc2[n] = __builtin_amdgcn_mfma_f32_16x16x32_bf16(a, b, acc2[n], 0, 0, 0);
        }
    }

    // ---- layer 2 epilogue ----
    {
        const float a2s = alpha2 * s1o;
#pragma unroll
        for (int n = 0; n < 8; ++n) {
            const int col = n * 16 + cl;
            const float bias = bias2[col];
            const int ks = n >> 1;
            const int gk = ((n & 1) * 2) + (cl >> 3);
            const int jd = cl & 7;
#pragma unroll
            for (int j = 0; j < 4; ++j) {
                const int rl = rh * 4 + j;
                float x = a2s * acc2[n][j] + bias;
                x = quantq_inv(x, inv_s2i) * s2i;
                x = fmaxf(x, 0.f);
                const float qv = quantq_inv(x, inv_s2o);
                __builtin_nontemporal_store(qv * s2o,
                    h2 + (size_t)(row0 + wq * 16 + rl) * 128 + col);
                A2[(((ks * 4 + wq) * 64) + (gk * 16 + rl)) * 8 + jd] =
                    (u16)(__float_as_uint(qv) >> 16);
            }
        }
    }

    // ---- layer 3: K=128, single ntile (N=10 padded to 16) ----
    f32x4 acc3 = f32x4{0.f, 0.f, 0.f, 0.f};
#pragma unroll
    for (int ks = 0; ks < 4; ++ks) {
        const bf16x8 a = *reinterpret_cast<const bf16x8*>(&A2[((ks * 4 + wq) * 64 + lane) * 8]);
        const bf16x8 b = *reinterpret_cast<const bf16x8*>(Wb3 + ((size_t)ks * 64 + lane) * 8);
        acc3 = __builtin_amdgcn_mfma_f32_16x16x32_bf16(a, b, acc3, 0, 0, 0);
    }

    // ---- layer 3 epilogue: sigmoid + quant, write h3 and out0 ----
    if (cl < 10) {
        const float a3s = alpha3 * s2o;
        const float bias = bias3[cl];
#pragma unroll
        for (int j = 0; j < 4; ++j) {
            const int rgl = row0 + wq * 16 + rh * 4 + j;
            float x = a3s * acc3[j] + bias;
            x = quantq_inv(x, inv_s3i) * s3i;
            const float sg = 1.f / (1.f + expf(-x));
            const float qv = quantq_inv(sg, inv_s3o) * s3o;
            out0[(size_t)rgl * 10 + cl] = qv;
            h3[(size_t)rgl * 10 + cl] = qv;
        }
    }
}

extern "C" void kernel_launch(void* const* d_in, const int* in_sizes, int n_in,
                              void* d_out, int out_size, void* d_ws, size_t ws_size,
                              hipStream_t stream) {
    const float* input = (const float*)d_in[0];
    const float* w1    = (const float*)d_in[1];
    const float* bias1 = (const float*)d_in[2];
    const float* w2    = (const float*)d_in[3];
    const float* bias2 = (const float*)d_in[4];
    const float* w3    = (const float*)d_in[5];
    const float* bias3 = (const float*)d_in[6];
    const float* s_in  = (const float*)d_in[7];
    const float* s1i   = (const float*)d_in[8];
    const float* s1o   = (const float*)d_in[9];
    const float* s2i   = (const float*)d_in[10];
    const float* s2o   = (const float*)d_in[11];
    const float* s3i   = (const float*)d_in[12];
    const float* s3o   = (const float*)d_in[13];

    float* out = (float*)d_out;
    // output order: (x_final, h0, h1, h2, h3)
    float* out0 = out;
    float* h0 = out + 655360;                   // 65536*10
    float* h1 = out + 52035584;                 // + 65536*784
    float* h2 = out + 60424192;                 // + 65536*128
    float* h3 = out + 68812800;                 // + 65536*128

    float* alphas  = (float*)d_ws;                        // 3 floats
    float* partial = (float*)((char*)d_ws + 16);          // 96 floats
    u16*   Wb1     = (u16*)((char*)d_ws + 512);           // 120832 u16

    alpha_part<<<96, 256, 0, stream>>>(w1, w2, w3, partial);
    pack_kernel<<<472, 256, 0, stream>>>(w1, w2, w3, Wb1, partial, alphas);
    fused_kernel<<<1024, 512, 0, stream>>>(input, bias1, bias2, bias3,
                                           s_in, s1i, s1o, s2i, s2o, s3i, s3o,
                                           alphas, Wb1,
                                           out0, h0, h1, h2, h3);
}

// Round 5
// 124.393 us; speedup vs baseline: 2.7004x; 2.7004x over previous
//
#include <hip/hip_runtime.h>
#include <math.h>

typedef __bf16 bf16x8 __attribute__((ext_vector_type(8)));
typedef float f32x4 __attribute__((ext_vector_type(4)));
typedef unsigned short u16;
typedef u16 u16x8 __attribute__((ext_vector_type(8)));

// clip(round(x*inv), -128, 127) -- rintf = round-half-even, matches jnp.round
__device__ __forceinline__ float quantq_inv(float x, float inv) {
    return fminf(fmaxf(rintf(x * inv), -128.f), 127.f);
}

__device__ __forceinline__ u16 sign_bf16(float w) {
    return (w > 0.f) ? (u16)0x3F80 : ((w < 0.f) ? (u16)0xBF80 : (u16)0);
}

// ---------------- prep 1: per-slice |w| partial sums (deterministic) --------
__global__ void alpha_part(const float* __restrict__ w1,
                           const float* __restrict__ w2,
                           const float* __restrict__ w3,
                           float* __restrict__ partial) {
    __shared__ float red[256];
    const int bid = blockIdx.x;
    const int m = bid >> 5, i = bid & 31;
    const float* w = (m == 0) ? w1 : ((m == 1) ? w2 : w3);
    const int n = (m == 0) ? 100352 : ((m == 1) ? 16384 : 1280);
    const int chunk = n >> 5;  // all divisible by 32
    const float* p = w + i * chunk;
    float s = 0.f;
    for (int t = threadIdx.x; t < chunk; t += 256) s += fabsf(p[t]);
    red[threadIdx.x] = s;
    __syncthreads();
    for (int off = 128; off > 0; off >>= 1) {
        if ((int)threadIdx.x < off) red[threadIdx.x] += red[threadIdx.x + off];
        __syncthreads();
    }
    if (threadIdx.x == 0) partial[bid] = red[0];
}

// ---------------- prep 2: pack sign(w) frag-ready + finalize alphas ---------
// dest layout per kstep(K=32): [ntile][lane][8] where for B-operand of
// mfma_f32_16x16x32_bf16: lane = (kk/8)*16 + (col%16), j = kk%8
__global__ void pack_kernel(const float* __restrict__ w1,
                            const float* __restrict__ w2,
                            const float* __restrict__ w3,
                            u16* __restrict__ Wb1,
                            const float* __restrict__ partial,
                            float* __restrict__ alphas) {
    if (blockIdx.x == 0 && threadIdx.x < 3) {
        const int t = threadIdx.x;
        float s = 0.f;
        for (int i = 0; i < 32; ++i) s += partial[t * 32 + i];
        const int n = (t == 0) ? 100352 : ((t == 1) ? 16384 : 1280);
        alphas[t] = s / (float)n;
    }
    u16* Wb2 = Wb1 + 102400;
    u16* Wb3 = Wb2 + 16384;
    int idx = blockIdx.x * 256 + threadIdx.x;
    if (idx < 102400) {
        int k = idx >> 7, n = idx & 127;
        u16 v = (k < 784) ? sign_bf16(w1[k * 128 + n]) : (u16)0;
        int dest = ((((k >> 5) * 8 + (n >> 4)) * 64) + ((((k & 31) >> 3) << 4) | (n & 15))) * 8 + (k & 7);
        Wb1[dest] = v;
    } else if (idx < 102400 + 16384) {
        int i = idx - 102400;
        int k = i >> 7, n = i & 127;
        u16 v = sign_bf16(w2[k * 128 + n]);
        int dest = ((((k >> 5) * 8 + (n >> 4)) * 64) + ((((k & 31) >> 3) << 4) | (n & 15))) * 8 + (k & 7);
        Wb2[dest] = v;
    } else if (idx < 102400 + 16384 + 2048) {
        int i = idx - 102400 - 16384;
        int k = i >> 4, n = i & 15;
        u16 v = (n < 10) ? sign_bf16(w3[k * 10 + n]) : (u16)0;
        int dest = (((k >> 5) * 64) + ((((k & 31) >> 3) << 4) | n)) * 8 + (k & 7);
        Wb3[dest] = v;
    }
}

// ---------------- fused forward: 64 rows/block, 8 waves, split-N pairs ------
// wq = wave&3 -> 16-row tile; nh = wave>>2 -> output-column half (4 ntiles).
// Pair waves duplicate the input quant (L1/L2 absorbs dup reads); only nh=0
// writes h0. acc per wave = 4 tiles (16 regs) so the hot loop fits the 64-reg
// occupancy granule without spilling (R4 post-mortem).
__global__ __launch_bounds__(512, 6) void fused_kernel(
    const float* __restrict__ input,
    const float* __restrict__ bias1, const float* __restrict__ bias2,
    const float* __restrict__ bias3,
    const float* __restrict__ ps_in, const float* __restrict__ ps1i,
    const float* __restrict__ ps1o, const float* __restrict__ ps2i,
    const float* __restrict__ ps2o, const float* __restrict__ ps3i,
    const float* __restrict__ ps3o,
    const float* __restrict__ alphas, const u16* __restrict__ Wb1,
    float* __restrict__ out0, float* __restrict__ h0, float* __restrict__ h1,
    float* __restrict__ h2, float* __restrict__ h3)
{
    const u16* Wb2 = Wb1 + 102400;
    const u16* Wb3 = Wb2 + 16384;

    __shared__ u16 A2[8192];   // 16KB: [ks(4)][wq(4)][lane(64)][8] (layer-2 A)
    __shared__ u16 A2b[8192];  // 16KB: same layout (layer-3 A)

    const int tid = threadIdx.x;
    const int wave = tid >> 6, lane = tid & 63;
    const int wq = wave & 3, nh = wave >> 2;
    const int row0 = blockIdx.x * 64;

    const float s_in = *ps_in, s1i = *ps1i, s1o = *ps1o;
    const float s2i = *ps2i, s2o = *ps2o, s3i = *ps3i, s3o = *ps3o;
    const float inv_sin = 1.f / s_in, inv_s1i = 1.f / s1i, inv_s1o = 1.f / s1o;
    const float inv_s2i = 1.f / s2i, inv_s2o = 1.f / s2o;
    const float inv_s3i = 1.f / s3i, inv_s3o = 1.f / s3o;
    const float alpha1 = alphas[0], alpha2 = alphas[1], alpha3 = alphas[2];

    // A-frag ownership: row = lane&15 (within wq's 16-row tile), kgroup = lane>>4
    const int rA = lane & 15;
    const int gA = lane >> 4;
    const size_t arow = (size_t)(row0 + wq * 16 + rA) * 784;
    const float* __restrict__ inA = input + arow + gA * 8;
    float* __restrict__ h0A = h0 + arow + gA * 8;
    // B base for this wave's 4 ntiles (nh picks ntiles 0-3 or 4-7)
    const u16* bw1 = Wb1 + (size_t)lane * 8 + nh * 2048;
    const u16* bw2 = Wb2 + (size_t)lane * 8 + nh * 2048;
    const bool storeh0 = (nh == 0);

    f32x4 acc1[4];
#pragma unroll
    for (int n = 0; n < 4; ++n) acc1[n] = f32x4{0.f, 0.f, 0.f, 0.f};

    // quant + h0-store + pack + 4 MFMAs for one kstep's 8 owned elements
    auto consume = [&](int ksq, f32x4 va, f32x4 vb, bool dostore) {
        float q[8];
#pragma unroll
        for (int j = 0; j < 4; ++j) {
            q[j]     = quantq_inv(va[j], inv_sin);
            q[4 + j] = quantq_inv(vb[j], inv_sin);
        }
        if (dostore) {
            f32x4 ha = {q[0] * s_in, q[1] * s_in, q[2] * s_in, q[3] * s_in};
            f32x4 hb = {q[4] * s_in, q[5] * s_in, q[6] * s_in, q[7] * s_in};
            float* hp = h0A + ksq * 32;
            __builtin_nontemporal_store(ha, reinterpret_cast<f32x4*>(hp));
            __builtin_nontemporal_store(hb, reinterpret_cast<f32x4*>(hp + 4));
        }
        u16x8 qb;
#pragma unroll
        for (int j = 0; j < 8; ++j) qb[j] = (u16)(__float_as_uint(q[j]) >> 16);
        union { u16x8 u; bf16x8 b; } cvt;
        cvt.u = qb;
        const bf16x8 a = cvt.b;
        const u16* bp = bw1 + (size_t)ksq * 4096;
#pragma unroll
        for (int n = 0; n < 4; ++n) {
            const bf16x8 b = *reinterpret_cast<const bf16x8*>(bp + n * 512);
            acc1[n] = __builtin_amdgcn_mfma_f32_16x16x32_bf16(a, b, acc1[n], 0, 0, 0);
        }
    };

    // ---- layer 1: K=784 padded to 800 (25 ksteps), 1-deep static prefetch --
    {
        f32x4 ca = *reinterpret_cast<const f32x4*>(inA);
        f32x4 cb = *reinterpret_cast<const f32x4*>(inA + 4);
#pragma unroll
        for (int k = 0; k < 25; ++k) {
            f32x4 na, nb;
            if (k < 23) {
                na = *reinterpret_cast<const f32x4*>(inA + (k + 1) * 32);
                nb = *reinterpret_cast<const f32x4*>(inA + (k + 1) * 32 + 4);
            } else if (k == 23) {
                if (gA < 2) {
                    na = *reinterpret_cast<const f32x4*>(inA + 768);
                    nb = *reinterpret_cast<const f32x4*>(inA + 768 + 4);
                } else {
                    na = f32x4{0.f, 0.f, 0.f, 0.f};
                    nb = f32x4{0.f, 0.f, 0.f, 0.f};
                }
            } else {
                na = ca; nb = cb;
            }
            // tail kstep 24 valid only for gA<2 (cols 768..784), zeros else
            consume(k, ca, cb, storeh0 && ((k < 24) || (gA < 2)));
            ca = na; cb = nb;
        }
    }

    // ---- layer 1 epilogue: requantize, write h1 (own col-half), stage A2 ---
    const int cl = lane & 15;
    const int rh = lane >> 4;
    {
        const float a1s = alpha1 * s_in;
#pragma unroll
        for (int np = 0; np < 4; ++np) {
            const int n = nh * 4 + np;
            const int col = n * 16 + cl;
            const float bias = bias1[col];
            const int ks = n >> 1;
            const int gk = ((n & 1) * 2) + (cl >> 3);
            const int jd = cl & 7;
#pragma unroll
            for (int j = 0; j < 4; ++j) {
                const int rl = rh * 4 + j;
                float x = a1s * acc1[np][j] + bias;
                x = quantq_inv(x, inv_s1i) * s1i;
                x = fmaxf(x, 0.f);
                const float qv = quantq_inv(x, inv_s1o);
                __builtin_nontemporal_store(qv * s1o,
                    h1 + (size_t)(row0 + wq * 16 + rl) * 128 + col);
                A2[(((ks * 4 + wq) * 64) + (gk * 16 + rl)) * 8 + jd] =
                    (u16)(__float_as_uint(qv) >> 16);
            }
        }
    }

    __syncthreads();  // A2 complete (both col-halves) before layer 2 reads

    // ---- layer 2: K=128 (4 ksteps), 4 ntiles per wave ----
    f32x4 acc2[4];
#pragma unroll
    for (int n = 0; n < 4; ++n) acc2[n] = f32x4{0.f, 0.f, 0.f, 0.f};
#pragma unroll
    for (int ks = 0; ks < 4; ++ks) {
        const bf16x8 a = *reinterpret_cast<const bf16x8*>(&A2[((ks * 4 + wq) * 64 + lane) * 8]);
        const u16* bp = bw2 + (size_t)ks * 4096;
#pragma unroll
        for (int n = 0; n < 4; ++n) {
            const bf16x8 b = *reinterpret_cast<const bf16x8*>(bp + n * 512);
            acc2[n] = __builtin_amdgcn_mfma_f32_16x16x32_bf16(a, b, acc2[n], 0, 0, 0);
        }
    }

    // ---- layer 2 epilogue: write h2 (own col-half), stage A2b ----
    {
        const float a2s = alpha2 * s1o;
#pragma unroll
        for (int np = 0; np < 4; ++np) {
            const int n = nh * 4 + np;
            const int col = n * 16 + cl;
            const float bias = bias2[col];
            const int ks = n >> 1;
            const int gk = ((n & 1) * 2) + (cl >> 3);
            const int jd = cl & 7;
#pragma unroll
            for (int j = 0; j < 4; ++j) {
                const int rl = rh * 4 + j;
                float x = a2s * acc2[np][j] + bias;
                x = quantq_inv(x, inv_s2i) * s2i;
                x = fmaxf(x, 0.f);
                const float qv = quantq_inv(x, inv_s2o);
                __builtin_nontemporal_store(qv * s2o,
                    h2 + (size_t)(row0 + wq * 16 + rl) * 128 + col);
                A2b[(((ks * 4 + wq) * 64) + (gk * 16 + rl)) * 8 + jd] =
                    (u16)(__float_as_uint(qv) >> 16);
            }
        }
    }

    __syncthreads();  // A2b complete before layer 3 reads
    if (nh == 1) return;  // layer 3 is a single ntile; col-half-0 waves only

    // ---- layer 3: K=128, single ntile (N=10 padded to 16) ----
    f32x4 acc3 = f32x4{0.f, 0.f, 0.f, 0.f};
#pragma unroll
    for (int ks = 0; ks < 4; ++ks) {
        const bf16x8 a = *reinterpret_cast<const bf16x8*>(&A2b[((ks * 4 + wq) * 64 + lane) * 8]);
        const bf16x8 b = *reinterpret_cast<const bf16x8*>(Wb3 + ((size_t)ks * 64 + lane) * 8);
        acc3 = __builtin_amdgcn_mfma_f32_16x16x32_bf16(a, b, acc3, 0, 0, 0);
    }

    // ---- layer 3 epilogue: sigmoid + quant, write h3 and out0 ----
    if (cl < 10) {
        const float a3s = alpha3 * s2o;
        const float bias = bias3[cl];
#pragma unroll
        for (int j = 0; j < 4; ++j) {
            const int rgl = row0 + wq * 16 + rh * 4 + j;
            float x = a3s * acc3[j] + bias;
            x = quantq_inv(x, inv_s3i) * s3i;
            const float sg = 1.f / (1.f + expf(-x));
            const float qv = quantq_inv(sg, inv_s3o) * s3o;
            out0[(size_t)rgl * 10 + cl] = qv;
            h3[(size_t)rgl * 10 + cl] = qv;
        }
    }
}

extern "C" void kernel_launch(void* const* d_in, const int* in_sizes, int n_in,
                              void* d_out, int out_size, void* d_ws, size_t ws_size,
                              hipStream_t stream) {
    const float* input = (const float*)d_in[0];
    const float* w1    = (const float*)d_in[1];
    const float* bias1 = (const float*)d_in[2];
    const float* w2    = (const float*)d_in[3];
    const float* bias2 = (const float*)d_in[4];
    const float* w3    = (const float*)d_in[5];
    const float* bias3 = (const float*)d_in[6];
    const float* s_in  = (const float*)d_in[7];
    const float* s1i   = (const float*)d_in[8];
    const float* s1o   = (const float*)d_in[9];
    const float* s2i   = (const float*)d_in[10];
    const float* s2o   = (const float*)d_in[11];
    const float* s3i   = (const float*)d_in[12];
    const float* s3o   = (const float*)d_in[13];

    float* out = (float*)d_out;
    // output order: (x_final, h0, h1, h2, h3)
    float* out0 = out;
    float* h0 = out + 655360;                   // 65536*10
    float* h1 = out + 52035584;                 // + 65536*784
    float* h2 = out + 60424192;                 // + 65536*128
    float* h3 = out + 68812800;                 // + 65536*128

    float* alphas  = (float*)d_ws;                        // 3 floats
    float* partial = (float*)((char*)d_ws + 16);          // 96 floats
    u16*   Wb1     = (u16*)((char*)d_ws + 512);           // 120832 u16

    alpha_part<<<96, 256, 0, stream>>>(w1, w2, w3, partial);
    pack_kernel<<<472, 256, 0, stream>>>(w1, w2, w3, Wb1, partial, alphas);
    fused_kernel<<<1024, 512, 0, stream>>>(input, bias1, bias2, bias3,
                                           s_in, s1i, s1o, s2i, s2o, s3i, s3o,
                                           alphas, Wb1,
                                           out0, h0, h1, h2, h3);
}